// Round 7
// baseline (443.438 us; speedup 1.0000x reference)
//
#include <hip/hip_runtime.h>
#include <hip/hip_bf16.h>
#include <math.h>

#define NN 1024
#define JS 64        // j-slice per block (16 slices)
#define PB 72        // BS row pitch (ushorts): 64 + 8 pad -> ~2-way banks, 16B-aligned
#define LP 40        // L row pitch (ushorts)
#define LROWS 85     // 21 (L1) + 63 (L2) + 1 pad row

typedef __attribute__((ext_vector_type(8))) short v8s;
typedef __attribute__((ext_vector_type(4))) float v4f;

#define MFMA(a, b, c) __builtin_amdgcn_mfma_f32_16x16x32_bf16((a), (b), (c), 0, 0, 0)

static __device__ __forceinline__ float silu_f(float x) {
    return x / (1.0f + __expf(-x));
}
static __device__ __forceinline__ unsigned short f2bf(float x) {
    __hip_bfloat16 h = __float2bfloat16(x);
    unsigned short u; __builtin_memcpy(&u, &h, 2); return u;
}
static __device__ __forceinline__ unsigned pack2bf(float lo, float hi) {
    __hip_bfloat162 h = __float22bfloat162_rn(make_float2(lo, hi));
    unsigned u; __builtin_memcpy(&u, &h, 4); return u;
}

// ---------------------------------------------------------------------------
// Kernel 1: per-node precompute -> RT[160][1024] bf16 (n-major, j contiguous).
// rows 0..31: lB[f]; 32..127: P[d,f]=v[j,d,f]*lA[f]; 128..159: lC[f].
// ---------------------------------------------------------------------------
extern "C" __global__ __launch_bounds__(128)
void node_kernel(const float* __restrict__ scalar,
                 const float* __restrict__ vector,
                 const float* __restrict__ mL_w1, const float* __restrict__ mL_b1,
                 const float* __restrict__ mL_w2, const float* __restrict__ mL_b2,
                 unsigned short* __restrict__ RT)
{
    const int j = blockIdx.x;
    const int t = threadIdx.x;
    __shared__ float ss[32], sh[32], sleft[96];

    if (t < 32) ss[t] = scalar[j * 32 + t];
    __syncthreads();
    if (t < 32) {
        float a = mL_b1[t];
        #pragma unroll
        for (int k = 0; k < 32; k++) a = fmaf(ss[k], mL_w1[k * 32 + t], a);
        sh[t] = silu_f(a);
    }
    __syncthreads();
    if (t < 96) {
        float a = mL_b2[t];
        #pragma unroll
        for (int k = 0; k < 32; k++) a = fmaf(sh[k], mL_w2[k * 96 + t], a);
        sleft[t] = a;
    }
    __syncthreads();
    for (int n = t; n < 160; n += 128) {
        float val;
        if (n < 32)        val = sleft[32 + n];
        else if (n < 128)  val = vector[j * 96 + (n - 32)] * sleft[(n - 32) & 31];
        else               val = sleft[64 + (n - 128)];
        RT[(size_t)n * NN + j] = f2bf(val);
    }
}

// ---------------------------------------------------------------------------
// Kernel 2: B-in-LDS batched MFMA. Block = (igroup of 8, jslice of 64).
// Each wave: 2 sequential i's, builds L1(21r)+L2(63r) per 32-j chunk, MFMAs
// against LDS-resident B slice, contracts acc, atomicAdds 224 partials.
// ---------------------------------------------------------------------------
extern "C" __global__ __launch_bounds__(256, 3)
void edge_mfma_kernel(const float* __restrict__ expansion,
                      const float* __restrict__ direction,
                      const float* __restrict__ mask,
                      const float* __restrict__ mR_w, const float* __restrict__ mR_b,
                      const unsigned short* __restrict__ RT,
                      float* __restrict__ part)
{
    const int t = threadIdx.x;
    const int wave = t >> 6;
    const int lane = t & 63;
    const int lrow = lane & 15;
    const int quad = lane >> 4;
    const int jp = lane >> 2;      // 0..15
    const int g  = lane & 3;
    const int jl = jp * 2;

    const int bx = blockIdx.x;
    const int slice = bx & 15;
    const int i0 = (bx >> 4) * 8;
    const int j0s = slice * JS;

    __shared__ __align__(16) unsigned short BSm[160 * PB];   // 23040 B
    __shared__ __align__(16) unsigned short Lm[4 * LROWS * LP]; // 27200 B

    // ---- stage B slice once ----
    for (int u = t; u < 160 * 8; u += 256) {
        const int row = u >> 3, seg = u & 7;
        *(uint4*)(BSm + row * PB + seg * 8) =
            *(const uint4*)(RT + (size_t)row * NN + j0s + seg * 8);
    }
    __syncthreads();

    unsigned short* L1 = Lm + wave * (LROWS * LP);
    unsigned short* L2 = L1 + 21 * LP;
    float* S = (float*)L1;   // epilogue scratch overlay (per-wave)

    v4f acc[24];
    #pragma unroll
    for (int q = 0; q < 24; ++q) acc[q] = (v4f){0.f, 0.f, 0.f, 0.f};

    const int iw = i0 + wave * 2;

    // prefetch for (it=0, ch=0)
    float4 fa, fb, ca, cb;
    float m0, m1, da0, da1, da2, db0, db1, db2;
    {
        const size_t jg = (size_t)iw * NN + j0s + jl;
        fa = *(const float4*)(expansion + jg * 20 + 4 * g);
        fb = *(const float4*)(expansion + (jg + 1) * 20 + 4 * g);
        ca = *(const float4*)(expansion + jg * 20 + 16);
        cb = *(const float4*)(expansion + (jg + 1) * 20 + 16);
        m0 = mask[jg]; m1 = mask[jg + 1];
        da0 = direction[jg * 3 + 0]; da1 = direction[jg * 3 + 1]; da2 = direction[jg * 3 + 2];
        db0 = direction[(jg + 1) * 3 + 0]; db1 = direction[(jg + 1) * 3 + 1]; db2 = direction[(jg + 1) * 3 + 2];
    }

    for (int it = 0; it < 2; ++it) {
        const int i = iw + it;
        for (int ch = 0; ch < 2; ++ch) {
            // ---- pack current chunk into L1/L2 (consumes prefetched regs) ----
            {
                const float pa0 = m0 * da0, pa1 = m0 * da1, pa2 = m0 * da2;
                const float pb0 = m1 * db0, pb1 = m1 * db1, pb2 = m1 * db2;
                const float ea[4] = {fa.x, fa.y, fa.z, fa.w};
                const float eb[4] = {fb.x, fb.y, fb.z, fb.w};
                const float caa[4] = {ca.x, ca.y, ca.z, ca.w};
                const float cbb[4] = {cb.x, cb.y, cb.z, cb.w};
                #pragma unroll
                for (int k = 0; k < 4; ++k)
                    *(unsigned*)(L1 + (4 * g + k) * LP + jl) = pack2bf(m0 * ea[k], m1 * eb[k]);
                if (g == 3) {
                    #pragma unroll
                    for (int k = 0; k < 4; ++k)
                        *(unsigned*)(L1 + (16 + k) * LP + jl) = pack2bf(m0 * caa[k], m1 * cbb[k]);
                }
                if (g == 0) *(unsigned*)(L1 + 20 * LP + jl) = pack2bf(m0, m1);

                const float pad[3] = {pa0, pa1, pa2};
                const float pbd[3] = {pb0, pb1, pb2};
                #pragma unroll
                for (int d = 0; d < 3; ++d)
                    #pragma unroll
                    for (int k = 0; k < 4; ++k)
                        *(unsigned*)(L2 + (d * 20 + 4 * g + k) * LP + jl) =
                            pack2bf(pad[d] * ea[k], pbd[d] * eb[k]);
                if (g < 3) {
                    const float sa = (g == 0) ? pa0 : ((g == 1) ? pa1 : pa2);
                    const float sb = (g == 0) ? pb0 : ((g == 1) ? pb1 : pb2);
                    #pragma unroll
                    for (int k = 0; k < 4; ++k)
                        *(unsigned*)(L2 + (g * 20 + 16 + k) * LP + jl) =
                            pack2bf(sa * caa[k], sb * cbb[k]);
                } else {
                    *(unsigned*)(L2 + (60 + 0) * LP + jl) = pack2bf(pa0, pb0);
                    *(unsigned*)(L2 + (60 + 1) * LP + jl) = pack2bf(pa1, pb1);
                    *(unsigned*)(L2 + (60 + 2) * LP + jl) = pack2bf(pa2, pb2);
                }
            }
            // ---- prefetch next chunk (redefines regs; no MFMA dependency) ----
            {
                const int u = it * 2 + ch;
                const int un = (u < 3) ? u + 1 : 3;
                const int itn = un >> 1, chn = un & 1;
                const size_t jg = (size_t)(iw + itn) * NN + j0s + chn * 32 + jl;
                fa = *(const float4*)(expansion + jg * 20 + 4 * g);
                fb = *(const float4*)(expansion + (jg + 1) * 20 + 4 * g);
                ca = *(const float4*)(expansion + jg * 20 + 16);
                cb = *(const float4*)(expansion + (jg + 1) * 20 + 16);
                m0 = mask[jg]; m1 = mask[jg + 1];
                da0 = direction[jg * 3 + 0]; da1 = direction[jg * 3 + 1]; da2 = direction[jg * 3 + 2];
                db0 = direction[(jg + 1) * 3 + 0]; db1 = direction[(jg + 1) * 3 + 1]; db2 = direction[(jg + 1) * 3 + 2];
            }
            // ---- frags + MFMA (LDS only) ----
            {
                const int ko = quad * 8;
                const int kl = ch * 32 + ko;
                const v8s a0 = *(const v8s*)(L1 + lrow * LP + ko);
                const v8s a1 = *(const v8s*)(L1 + (16 + lrow) * LP + ko);
                #pragma unroll
                for (int nt = 0; nt < 8; ++nt) {
                    const v8s b = *(const v8s*)(BSm + (nt * 16 + lrow) * PB + kl);
                    acc[nt]     = MFMA(a0, b, acc[nt]);
                    acc[8 + nt] = MFMA(a1, b, acc[8 + nt]);
                }
                const v8s c0 = *(const v8s*)(L2 + (lrow) * LP + ko);
                const v8s c1 = *(const v8s*)(L2 + (16 + lrow) * LP + ko);
                const v8s c2 = *(const v8s*)(L2 + (32 + lrow) * LP + ko);
                const v8s c3 = *(const v8s*)(L2 + (48 + lrow) * LP + ko);
                const v8s b0 = *(const v8s*)(BSm + (128 + lrow) * PB + kl);
                const v8s b1 = *(const v8s*)(BSm + (144 + lrow) * PB + kl);
                acc[16] = MFMA(c0, b0, acc[16]); acc[17] = MFMA(c0, b1, acc[17]);
                acc[18] = MFMA(c1, b0, acc[18]); acc[19] = MFMA(c1, b1, acc[19]);
                acc[20] = MFMA(c2, b0, acc[20]); acc[21] = MFMA(c2, b1, acc[21]);
                acc[22] = MFMA(c3, b0, acc[22]); acc[23] = MFMA(c3, b1, acc[23]);
            }
        }

        // ---- per-i epilogue: contract acc -> 224 partials, atomic add ----
        // T1: two passes of 64 cols
        #pragma unroll
        for (int h = 0; h < 2; ++h) {
            #pragma unroll
            for (int mt = 0; mt < 2; ++mt)
            #pragma unroll
            for (int q = 0; q < 4; ++q)
            #pragma unroll
            for (int r = 0; r < 4; ++r) {
                const int row = mt * 16 + quad * 4 + r;
                if (row <= 20) S[row * 64 + q * 16 + lrow] = acc[mt * 8 + h * 4 + q][r];
            }
            const int col = h * 64 + lane;
            const int fw = (col < 32) ? (32 + col) : ((col - 32) & 31);
            float v = mR_b[fw] * S[20 * 64 + lane];
            #pragma unroll
            for (int e = 0; e < 20; ++e) v = fmaf(mR_w[e * 96 + fw], S[e * 64 + lane], v);
            atomicAdd(part + (size_t)i * 224 + col, v);
        }
        // T2: two passes of 16 cols
        #pragma unroll
        for (int h2 = 0; h2 < 2; ++h2) {
            #pragma unroll
            for (int mt = 0; mt < 4; ++mt)
            #pragma unroll
            for (int r = 0; r < 4; ++r) {
                const int row = mt * 16 + quad * 4 + r;
                if (row <= 62) S[row * 16 + lrow] = acc[16 + mt * 2 + h2][r];
            }
            if (lane < 48) {
                const int dd = lane >> 4, f16 = lane & 15;
                const int f = h2 * 16 + f16;
                float v = mR_b[64 + f] * S[(60 + dd) * 16 + f16];
                #pragma unroll
                for (int e = 0; e < 20; ++e)
                    v = fmaf(mR_w[e * 96 + 64 + f], S[(dd * 20 + e) * 16 + f16], v);
                atomicAdd(part + (size_t)i * 224 + 128 + dd * 32 + f, v);
            }
        }
        #pragma unroll
        for (int q = 0; q < 24; ++q) acc[q] = (v4f){0.f, 0.f, 0.f, 0.f};
    }
}

// ---------------------------------------------------------------------------
// Kernel 3: combine partials + update phase, one block per row (r3-proven).
// ---------------------------------------------------------------------------
extern "C" __global__ __launch_bounds__(256)
void combine_kernel(const float* __restrict__ scalar,
                    const float* __restrict__ vector,
                    const float* __restrict__ uR_w1, const float* __restrict__ uR_b1,
                    const float* __restrict__ uR_w2, const float* __restrict__ uR_b2,
                    const float* __restrict__ U_w,  const float* __restrict__ V_w,
                    const float* __restrict__ part,
                    float* __restrict__ out)
{
    const int i = blockIdx.x;
    const int t = threadIdx.x;
    __shared__ float snew[32], vnew[96];
    __shared__ float lU[96], rV[96], rnorm[32], h2[32], f2[96];

    if (t < 128) {
        float a = part[(size_t)i * 224 + t];
        if (t >= 32) a += part[(size_t)i * 224 + 96 + t];   // ΔVc at 128+(t-32)
        const int d = t >> 5, ff = t & 31;
        if (d == 0) snew[ff] = scalar[i * 32 + ff] + a;
        else        vnew[(d - 1) * 32 + ff] = vector[i * 96 + (d - 1) * 32 + ff] + a;
    }
    __syncthreads();

    if (t < 96) {
        const int d = t >> 5, ff = t & 31;
        float a = 0.0f;
        #pragma unroll
        for (int k = 0; k < 32; k++) a = fmaf(vnew[d * 32 + k], U_w[k * 32 + ff], a);
        lU[t] = a;
    } else if (t >= 128 && t < 224) {
        const int dt = t - 128, d = dt >> 5, ff = dt & 31;
        float a = 0.0f;
        #pragma unroll
        for (int k = 0; k < 32; k++) a = fmaf(vnew[d * 32 + k], V_w[k * 32 + ff], a);
        rV[dt] = a;
    }
    __syncthreads();
    if (t < 32) {
        const float a = rV[t] * rV[t] + rV[32 + t] * rV[32 + t] + rV[64 + t] * rV[64 + t];
        rnorm[t] = sqrtf(a);
    }
    __syncthreads();
    if (t < 32) {
        float a = uR_b1[t];
        #pragma unroll
        for (int k = 0; k < 32; k++) a = fmaf(snew[k],  uR_w1[k * 32 + t], a);
        #pragma unroll
        for (int k = 0; k < 32; k++) a = fmaf(rnorm[k], uR_w1[(32 + k) * 32 + t], a);
        h2[t] = silu_f(a);
    }
    __syncthreads();
    if (t < 96) {
        float a = uR_b2[t];
        #pragma unroll
        for (int k = 0; k < 32; k++) a = fmaf(h2[k], uR_w2[k * 96 + t], a);
        f2[t] = a;
    }
    __syncthreads();
    if (t < 32) {
        const float inner = lU[t] * rV[t] + lU[32 + t] * rV[32 + t] + lU[64 + t] * rV[64 + t];
        out[i * 32 + t] = snew[t] + inner * f2[32 + t] + f2[64 + t];
    } else if (t >= 64 && t < 160) {
        const int dt = t - 64, ff = dt & 31;
        out[32768 + i * 96 + dt] = vnew[dt] + f2[ff] * lU[dt];
    }
}

extern "C" void kernel_launch(void* const* d_in, const int* in_sizes, int n_in,
                              void* d_out, int out_size, void* d_ws, size_t ws_size,
                              hipStream_t stream) {
    const float* scalar    = (const float*)d_in[0];
    const float* vector    = (const float*)d_in[1];
    const float* expansion = (const float*)d_in[2];
    const float* direction = (const float*)d_in[3];
    const float* mask      = (const float*)d_in[4];
    const float* mL_w1     = (const float*)d_in[5];
    const float* mL_b1     = (const float*)d_in[6];
    const float* mL_w2     = (const float*)d_in[7];
    const float* mL_b2     = (const float*)d_in[8];
    const float* mR_w      = (const float*)d_in[9];
    const float* mR_b      = (const float*)d_in[10];
    const float* uR_w1     = (const float*)d_in[11];
    const float* uR_b1     = (const float*)d_in[12];
    const float* uR_w2     = (const float*)d_in[13];
    const float* uR_b2     = (const float*)d_in[14];
    const float* U_w       = (const float*)d_in[15];
    const float* V_w       = (const float*)d_in[16];
    float* out = (float*)d_out;

    unsigned short* RT = (unsigned short*)d_ws;                 // 320 KB
    float* part = (float*)((char*)d_ws + 160 * NN * 2);         // 1024*224*4 = 896 KB

    hipLaunchKernelGGL(node_kernel, dim3(NN), dim3(128), 0, stream,
                       scalar, vector, mL_w1, mL_b1, mL_w2, mL_b2, RT);
    hipMemsetAsync(part, 0, (size_t)NN * 224 * sizeof(float), stream);
    hipLaunchKernelGGL(edge_mfma_kernel, dim3(2048), dim3(256), 0, stream,
                       expansion, direction, mask, mR_w, mR_b, RT, part);
    hipLaunchKernelGGL(combine_kernel, dim3(NN), dim3(256), 0, stream,
                       scalar, vector, uR_w1, uR_b1, uR_w2, uR_b2, U_w, V_w,
                       part, out);
}

// Round 8
// 434.940 us; speedup vs baseline: 1.0195x; 1.0195x over previous
//
#include <hip/hip_runtime.h>
#include <hip/hip_bf16.h>
#include <math.h>

#define NN 1024
#define JS 64        // j-slice per block (16 slices)
#define NSL 16       // number of slices
#define PB 72        // BS row pitch (ushorts)
#define LP 40        // L row pitch (ushorts)
#define LROWS 85     // 21 (L1) + 63 (L2) + 1 pad row

typedef __attribute__((ext_vector_type(8))) short v8s;
typedef __attribute__((ext_vector_type(4))) float v4f;

#define MFMA(a, b, c) __builtin_amdgcn_mfma_f32_16x16x32_bf16((a), (b), (c), 0, 0, 0)

static __device__ __forceinline__ float silu_f(float x) {
    return x / (1.0f + __expf(-x));
}
static __device__ __forceinline__ unsigned short f2bf(float x) {
    __hip_bfloat16 h = __float2bfloat16(x);
    unsigned short u; __builtin_memcpy(&u, &h, 2); return u;
}
static __device__ __forceinline__ unsigned pack2bf(float lo, float hi) {
    __hip_bfloat162 h = __float22bfloat162_rn(make_float2(lo, hi));
    unsigned u; __builtin_memcpy(&u, &h, 4); return u;
}

// ---------------------------------------------------------------------------
// Kernel 1: per-node precompute -> RT[160][1024] bf16 (n-major, j contiguous).
// rows 0..31: lB[f]; 32..127: P[d,f]=v[j,d,f]*lA[f]; 128..159: lC[f].
// ---------------------------------------------------------------------------
extern "C" __global__ __launch_bounds__(128)
void node_kernel(const float* __restrict__ scalar,
                 const float* __restrict__ vector,
                 const float* __restrict__ mL_w1, const float* __restrict__ mL_b1,
                 const float* __restrict__ mL_w2, const float* __restrict__ mL_b2,
                 unsigned short* __restrict__ RT)
{
    const int j = blockIdx.x;
    const int t = threadIdx.x;
    __shared__ float ss[32], sh[32], sleft[96];

    if (t < 32) ss[t] = scalar[j * 32 + t];
    __syncthreads();
    if (t < 32) {
        float a = mL_b1[t];
        #pragma unroll
        for (int k = 0; k < 32; k++) a = fmaf(ss[k], mL_w1[k * 32 + t], a);
        sh[t] = silu_f(a);
    }
    __syncthreads();
    if (t < 96) {
        float a = mL_b2[t];
        #pragma unroll
        for (int k = 0; k < 32; k++) a = fmaf(sh[k], mL_w2[k * 96 + t], a);
        sleft[t] = a;
    }
    __syncthreads();
    for (int n = t; n < 160; n += 128) {
        float val;
        if (n < 32)        val = sleft[32 + n];
        else if (n < 128)  val = vector[j * 96 + (n - 32)] * sleft[(n - 32) & 31];
        else               val = sleft[64 + (n - 128)];
        RT[(size_t)n * NN + j] = f2bf(val);
    }
}

// ---------------------------------------------------------------------------
// Kernel 2: B-in-LDS batched MFMA. Block = (igroup of 8, jslice of 64).
// Each wave: 2 sequential i's; MFMA path is LDS-only; per-(i,slice) partials
// written with PLAIN coalesced stores (single static writer — no atomics).
// ---------------------------------------------------------------------------
extern "C" __global__ __launch_bounds__(256, 3)
void edge_mfma_kernel(const float* __restrict__ expansion,
                      const float* __restrict__ direction,
                      const float* __restrict__ mask,
                      const float* __restrict__ mR_w, const float* __restrict__ mR_b,
                      const unsigned short* __restrict__ RT,
                      float* __restrict__ part)
{
    const int t = threadIdx.x;
    const int wave = t >> 6;
    const int lane = t & 63;
    const int lrow = lane & 15;
    const int quad = lane >> 4;
    const int jp = lane >> 2;      // 0..15
    const int g  = lane & 3;
    const int jl = jp * 2;

    const int bx = blockIdx.x;
    const int slice = bx & 15;
    const int i0 = (bx >> 4) * 8;
    const int j0s = slice * JS;

    __shared__ __align__(16) unsigned short BSm[160 * PB];      // 23040 B
    __shared__ __align__(16) unsigned short Lm[4 * LROWS * LP]; // 27200 B

    // ---- stage B slice once ----
    for (int u = t; u < 160 * 8; u += 256) {
        const int row = u >> 3, seg = u & 7;
        *(uint4*)(BSm + row * PB + seg * 8) =
            *(const uint4*)(RT + (size_t)row * NN + j0s + seg * 8);
    }
    __syncthreads();

    unsigned short* L1 = Lm + wave * (LROWS * LP);
    unsigned short* L2 = L1 + 21 * LP;
    float* S = (float*)L1;   // epilogue scratch overlay (per-wave)

    v4f acc[24];
    #pragma unroll
    for (int q = 0; q < 24; ++q) acc[q] = (v4f){0.f, 0.f, 0.f, 0.f};

    const int iw = i0 + wave * 2;

    // prefetch for (it=0, ch=0)
    float4 fa, fb, ca, cb;
    float m0, m1, da0, da1, da2, db0, db1, db2;
    {
        const size_t jg = (size_t)iw * NN + j0s + jl;
        fa = *(const float4*)(expansion + jg * 20 + 4 * g);
        fb = *(const float4*)(expansion + (jg + 1) * 20 + 4 * g);
        ca = *(const float4*)(expansion + jg * 20 + 16);
        cb = *(const float4*)(expansion + (jg + 1) * 20 + 16);
        m0 = mask[jg]; m1 = mask[jg + 1];
        da0 = direction[jg * 3 + 0]; da1 = direction[jg * 3 + 1]; da2 = direction[jg * 3 + 2];
        db0 = direction[(jg + 1) * 3 + 0]; db1 = direction[(jg + 1) * 3 + 1]; db2 = direction[(jg + 1) * 3 + 2];
    }

    for (int it = 0; it < 2; ++it) {
        const int i = iw + it;
        for (int ch = 0; ch < 2; ++ch) {
            // ---- pack current chunk into L1/L2 (consumes prefetched regs) ----
            {
                const float pa0 = m0 * da0, pa1 = m0 * da1, pa2 = m0 * da2;
                const float pb0 = m1 * db0, pb1 = m1 * db1, pb2 = m1 * db2;
                const float ea[4] = {fa.x, fa.y, fa.z, fa.w};
                const float eb[4] = {fb.x, fb.y, fb.z, fb.w};
                const float caa[4] = {ca.x, ca.y, ca.z, ca.w};
                const float cbb[4] = {cb.x, cb.y, cb.z, cb.w};
                #pragma unroll
                for (int k = 0; k < 4; ++k)
                    *(unsigned*)(L1 + (4 * g + k) * LP + jl) = pack2bf(m0 * ea[k], m1 * eb[k]);
                if (g == 3) {
                    #pragma unroll
                    for (int k = 0; k < 4; ++k)
                        *(unsigned*)(L1 + (16 + k) * LP + jl) = pack2bf(m0 * caa[k], m1 * cbb[k]);
                }
                if (g == 0) *(unsigned*)(L1 + 20 * LP + jl) = pack2bf(m0, m1);

                const float pad[3] = {pa0, pa1, pa2};
                const float pbd[3] = {pb0, pb1, pb2};
                #pragma unroll
                for (int d = 0; d < 3; ++d)
                    #pragma unroll
                    for (int k = 0; k < 4; ++k)
                        *(unsigned*)(L2 + (d * 20 + 4 * g + k) * LP + jl) =
                            pack2bf(pad[d] * ea[k], pbd[d] * eb[k]);
                if (g < 3) {
                    const float sa = (g == 0) ? pa0 : ((g == 1) ? pa1 : pa2);
                    const float sb = (g == 0) ? pb0 : ((g == 1) ? pb1 : pb2);
                    #pragma unroll
                    for (int k = 0; k < 4; ++k)
                        *(unsigned*)(L2 + (g * 20 + 16 + k) * LP + jl) =
                            pack2bf(sa * caa[k], sb * cbb[k]);
                } else {
                    *(unsigned*)(L2 + (60 + 0) * LP + jl) = pack2bf(pa0, pb0);
                    *(unsigned*)(L2 + (60 + 1) * LP + jl) = pack2bf(pa1, pb1);
                    *(unsigned*)(L2 + (60 + 2) * LP + jl) = pack2bf(pa2, pb2);
                }
            }
            // ---- prefetch next chunk (redefines regs; no MFMA dependency) ----
            {
                const int u = it * 2 + ch;
                const int un = (u < 3) ? u + 1 : 3;
                const int itn = un >> 1, chn = un & 1;
                const size_t jg = (size_t)(iw + itn) * NN + j0s + chn * 32 + jl;
                fa = *(const float4*)(expansion + jg * 20 + 4 * g);
                fb = *(const float4*)(expansion + (jg + 1) * 20 + 4 * g);
                ca = *(const float4*)(expansion + jg * 20 + 16);
                cb = *(const float4*)(expansion + (jg + 1) * 20 + 16);
                m0 = mask[jg]; m1 = mask[jg + 1];
                da0 = direction[jg * 3 + 0]; da1 = direction[jg * 3 + 1]; da2 = direction[jg * 3 + 2];
                db0 = direction[(jg + 1) * 3 + 0]; db1 = direction[(jg + 1) * 3 + 1]; db2 = direction[(jg + 1) * 3 + 2];
            }
            // ---- frags + MFMA (LDS only) ----
            {
                const int ko = quad * 8;
                const int kl = ch * 32 + ko;
                const v8s a0 = *(const v8s*)(L1 + lrow * LP + ko);
                const v8s a1 = *(const v8s*)(L1 + (16 + lrow) * LP + ko);
                #pragma unroll
                for (int nt = 0; nt < 8; ++nt) {
                    const v8s b = *(const v8s*)(BSm + (nt * 16 + lrow) * PB + kl);
                    acc[nt]     = MFMA(a0, b, acc[nt]);
                    acc[8 + nt] = MFMA(a1, b, acc[8 + nt]);
                }
                const v8s c0 = *(const v8s*)(L2 + (lrow) * LP + ko);
                const v8s c1 = *(const v8s*)(L2 + (16 + lrow) * LP + ko);
                const v8s c2 = *(const v8s*)(L2 + (32 + lrow) * LP + ko);
                const v8s c3 = *(const v8s*)(L2 + (48 + lrow) * LP + ko);
                const v8s b0 = *(const v8s*)(BSm + (128 + lrow) * PB + kl);
                const v8s b1 = *(const v8s*)(BSm + (144 + lrow) * PB + kl);
                acc[16] = MFMA(c0, b0, acc[16]); acc[17] = MFMA(c0, b1, acc[17]);
                acc[18] = MFMA(c1, b0, acc[18]); acc[19] = MFMA(c1, b1, acc[19]);
                acc[20] = MFMA(c2, b0, acc[20]); acc[21] = MFMA(c2, b1, acc[21]);
                acc[22] = MFMA(c3, b0, acc[22]); acc[23] = MFMA(c3, b1, acc[23]);
            }
        }

        // ---- per-i epilogue: contract acc -> 224 partials, plain stores ----
        float* pdst = part + ((size_t)i * NSL + slice) * 224;
        // T1: two passes of 64 cols
        #pragma unroll
        for (int h = 0; h < 2; ++h) {
            #pragma unroll
            for (int mt = 0; mt < 2; ++mt)
            #pragma unroll
            for (int q = 0; q < 4; ++q)
            #pragma unroll
            for (int r = 0; r < 4; ++r) {
                const int row = mt * 16 + quad * 4 + r;
                if (row <= 20) S[row * 64 + q * 16 + lrow] = acc[mt * 8 + h * 4 + q][r];
            }
            const int col = h * 64 + lane;
            const int fw = (col < 32) ? (32 + col) : ((col - 32) & 31);
            float v = mR_b[fw] * S[20 * 64 + lane];
            #pragma unroll
            for (int e = 0; e < 20; ++e) v = fmaf(mR_w[e * 96 + fw], S[e * 64 + lane], v);
            pdst[col] = v;
        }
        // T2: two passes of 16 cols
        #pragma unroll
        for (int h2 = 0; h2 < 2; ++h2) {
            #pragma unroll
            for (int mt = 0; mt < 4; ++mt)
            #pragma unroll
            for (int r = 0; r < 4; ++r) {
                const int row = mt * 16 + quad * 4 + r;
                if (row <= 62) S[row * 16 + lrow] = acc[16 + mt * 2 + h2][r];
            }
            if (lane < 48) {
                const int dd = lane >> 4, f16 = lane & 15;
                const int f = h2 * 16 + f16;
                float v = mR_b[64 + f] * S[(60 + dd) * 16 + f16];
                #pragma unroll
                for (int e = 0; e < 20; ++e)
                    v = fmaf(mR_w[e * 96 + 64 + f], S[(dd * 20 + e) * 16 + f16], v);
                pdst[128 + dd * 32 + f] = v;
            }
        }
        #pragma unroll
        for (int q = 0; q < 24; ++q) acc[q] = (v4f){0.f, 0.f, 0.f, 0.f};
    }
}

// ---------------------------------------------------------------------------
// Kernel 3: sum 16 slice-partials + update phase, one block per row.
// ---------------------------------------------------------------------------
extern "C" __global__ __launch_bounds__(256)
void combine_kernel(const float* __restrict__ scalar,
                    const float* __restrict__ vector,
                    const float* __restrict__ uR_w1, const float* __restrict__ uR_b1,
                    const float* __restrict__ uR_w2, const float* __restrict__ uR_b2,
                    const float* __restrict__ U_w,  const float* __restrict__ V_w,
                    const float* __restrict__ part,
                    float* __restrict__ out)
{
    const int i = blockIdx.x;
    const int t = threadIdx.x;
    __shared__ float pcomb[224];
    __shared__ float snew[32], vnew[96];
    __shared__ float lU[96], rV[96], rnorm[32], h2[32], f2[96];

    if (t < 224) {
        const float* p = part + (size_t)i * NSL * 224 + t;
        float a = 0.f;
        #pragma unroll
        for (int s = 0; s < NSL; ++s) a += p[s * 224];
        pcomb[t] = a;
    }
    __syncthreads();

    if (t < 128) {
        const int d = t >> 5, ff = t & 31;
        if (d == 0) snew[ff] = scalar[i * 32 + ff] + pcomb[ff];
        else {
            const int q = t - 32;
            vnew[q] = vector[i * 96 + q] + pcomb[32 + q] + pcomb[128 + q];
        }
    }
    __syncthreads();

    if (t < 96) {
        const int d = t >> 5, ff = t & 31;
        float a = 0.0f;
        #pragma unroll
        for (int k = 0; k < 32; k++) a = fmaf(vnew[d * 32 + k], U_w[k * 32 + ff], a);
        lU[t] = a;
    } else if (t >= 128 && t < 224) {
        const int dt = t - 128, d = dt >> 5, ff = dt & 31;
        float a = 0.0f;
        #pragma unroll
        for (int k = 0; k < 32; k++) a = fmaf(vnew[d * 32 + k], V_w[k * 32 + ff], a);
        rV[dt] = a;
    }
    __syncthreads();
    if (t < 32) {
        const float a = rV[t] * rV[t] + rV[32 + t] * rV[32 + t] + rV[64 + t] * rV[64 + t];
        rnorm[t] = sqrtf(a);
    }
    __syncthreads();
    if (t < 32) {
        float a = uR_b1[t];
        #pragma unroll
        for (int k = 0; k < 32; k++) a = fmaf(snew[k],  uR_w1[k * 32 + t], a);
        #pragma unroll
        for (int k = 0; k < 32; k++) a = fmaf(rnorm[k], uR_w1[(32 + k) * 32 + t], a);
        h2[t] = silu_f(a);
    }
    __syncthreads();
    if (t < 96) {
        float a = uR_b2[t];
        #pragma unroll
        for (int k = 0; k < 32; k++) a = fmaf(h2[k], uR_w2[k * 96 + t], a);
        f2[t] = a;
    }
    __syncthreads();
    if (t < 32) {
        const float inner = lU[t] * rV[t] + lU[32 + t] * rV[32 + t] + lU[64 + t] * rV[64 + t];
        out[i * 32 + t] = snew[t] + inner * f2[32 + t] + f2[64 + t];
    } else if (t >= 64 && t < 160) {
        const int dt = t - 64, ff = dt & 31;
        out[32768 + i * 96 + dt] = vnew[dt] + f2[ff] * lU[dt];
    }
}

extern "C" void kernel_launch(void* const* d_in, const int* in_sizes, int n_in,
                              void* d_out, int out_size, void* d_ws, size_t ws_size,
                              hipStream_t stream) {
    const float* scalar    = (const float*)d_in[0];
    const float* vector    = (const float*)d_in[1];
    const float* expansion = (const float*)d_in[2];
    const float* direction = (const float*)d_in[3];
    const float* mask      = (const float*)d_in[4];
    const float* mL_w1     = (const float*)d_in[5];
    const float* mL_b1     = (const float*)d_in[6];
    const float* mL_w2     = (const float*)d_in[7];
    const float* mL_b2     = (const float*)d_in[8];
    const float* mR_w      = (const float*)d_in[9];
    const float* mR_b      = (const float*)d_in[10];
    const float* uR_w1     = (const float*)d_in[11];
    const float* uR_b1     = (const float*)d_in[12];
    const float* uR_w2     = (const float*)d_in[13];
    const float* uR_b2     = (const float*)d_in[14];
    const float* U_w       = (const float*)d_in[15];
    const float* V_w       = (const float*)d_in[16];
    float* out = (float*)d_out;

    unsigned short* RT = (unsigned short*)d_ws;                 // 320 KB
    float* part = (float*)((char*)d_ws + 160 * NN * 2);         // 1024*16*224*4 = 14.7 MB

    hipLaunchKernelGGL(node_kernel, dim3(NN), dim3(128), 0, stream,
                       scalar, vector, mL_w1, mL_b1, mL_w2, mL_b2, RT);
    hipLaunchKernelGGL(edge_mfma_kernel, dim3(2048), dim3(256), 0, stream,
                       expansion, direction, mask, mR_w, mR_b, RT, part);
    hipLaunchKernelGGL(combine_kernel, dim3(NN), dim3(256), 0, stream,
                       scalar, vector, uR_w1, uR_b1, uR_w2, uR_b2, U_w, V_w,
                       part, out);
}

// Round 9
// 211.132 us; speedup vs baseline: 2.1003x; 2.0600x over previous
//
#include <hip/hip_runtime.h>
#include <hip/hip_bf16.h>
#include <math.h>

#define NN 1024
#define JS 64        // j-slice per block (16 slices)
#define NSL 16       // number of slices
#define PB 72        // BSm row pitch (ushorts)
#define LP 40        // L row pitch (ushorts)
#define WBUF 5376    // per-wave union buffer bytes: max(L1 1680, L2 5040, S1 5376, S2 4032)

typedef __attribute__((ext_vector_type(8))) short v8s;
typedef __attribute__((ext_vector_type(4))) float v4f;

#define MFMA(a, b, c) __builtin_amdgcn_mfma_f32_16x16x32_bf16((a), (b), (c), 0, 0, 0)

static __device__ __forceinline__ float silu_f(float x) {
    return x / (1.0f + __expf(-x));
}
static __device__ __forceinline__ unsigned short f2bf(float x) {
    __hip_bfloat16 h = __float2bfloat16(x);
    unsigned short u; __builtin_memcpy(&u, &h, 2); return u;
}
static __device__ __forceinline__ unsigned pack2bf(float lo, float hi) {
    __hip_bfloat162 h = __float22bfloat162_rn(make_float2(lo, hi));
    unsigned u; __builtin_memcpy(&u, &h, 4); return u;
}

// ---------------------------------------------------------------------------
// Kernel 1: per-node precompute -> RT[160][1024] bf16 (n-major, j contiguous).
// rows 0..31: lB[f]; 32..127: P[d,f]=v[j,d,f]*lA[f]; 128..159: lC[f].
// ---------------------------------------------------------------------------
extern "C" __global__ __launch_bounds__(128)
void node_kernel(const float* __restrict__ scalar,
                 const float* __restrict__ vector,
                 const float* __restrict__ mL_w1, const float* __restrict__ mL_b1,
                 const float* __restrict__ mL_w2, const float* __restrict__ mL_b2,
                 unsigned short* __restrict__ RT)
{
    const int j = blockIdx.x;
    const int t = threadIdx.x;
    __shared__ float ss[32], sh[32], sleft[96];

    if (t < 32) ss[t] = scalar[j * 32 + t];
    __syncthreads();
    if (t < 32) {
        float a = mL_b1[t];
        #pragma unroll
        for (int k = 0; k < 32; k++) a = fmaf(ss[k], mL_w1[k * 32 + t], a);
        sh[t] = silu_f(a);
    }
    __syncthreads();
    if (t < 96) {
        float a = mL_b2[t];
        #pragma unroll
        for (int k = 0; k < 32; k++) a = fmaf(sh[k], mL_w2[k * 96 + t], a);
        sleft[t] = a;
    }
    __syncthreads();
    for (int n = t; n < 160; n += 128) {
        float val;
        if (n < 32)        val = sleft[32 + n];
        else if (n < 128)  val = vector[j * 96 + (n - 32)] * sleft[(n - 32) & 31];
        else               val = sleft[64 + (n - 128)];
        RT[(size_t)n * NN + j] = f2bf(val);
    }
}

// ---------------------------------------------------------------------------
// Kernel 2: B-in-LDS, wave-specialized. Block = (igroup of 4, jslice of 64).
// Waves 0/2: T1 GEMM (16 acc) for i-pair; waves 1/3: T2 GEMM (8 acc).
// MFMA path LDS-only; plain disjoint stores of per-(i,slice) partials.
// Max ~130 unified regs/thread -> no spill at 3 waves/SIMD.
// ---------------------------------------------------------------------------
extern "C" __global__ __launch_bounds__(256, 3)
void edge_mfma_kernel(const float* __restrict__ expansion,
                      const float* __restrict__ direction,
                      const float* __restrict__ mask,
                      const float* __restrict__ mR_w, const float* __restrict__ mR_b,
                      const unsigned short* __restrict__ RT,
                      float* __restrict__ part)
{
    const int t = threadIdx.x;
    const int wave = t >> 6;
    const int lane = t & 63;
    const int lrow = lane & 15;
    const int quad = lane >> 4;
    const int jp = lane >> 2;      // 0..15
    const int g  = lane & 3;
    const int jl = jp * 2;

    const int bx = blockIdx.x;
    const int slice = bx & 15;
    const int i0 = (bx >> 4) * 4;
    const int j0s = slice * JS;

    __shared__ __align__(16) unsigned short BSm[160 * PB];   // 23040 B
    __shared__ __align__(16) char Wm[4 * WBUF];              // 21504 B

    // ---- stage B slice once ----
    for (int u = t; u < 160 * 8; u += 256) {
        const int row = u >> 3, seg = u & 7;
        *(uint4*)(BSm + row * PB + seg * 8) =
            *(const uint4*)(RT + (size_t)row * NN + j0s + seg * 8);
    }
    __syncthreads();

    char* wbase = Wm + wave * WBUF;
    const int ibase = i0 + (wave >> 1) * 2;

    if ((wave & 1) == 0) {
        // ================= T1 wave: rows {m*exp_e (20), m} x B[0..127] ======
        unsigned short* L1 = (unsigned short*)wbase;   // [21][LP]
        float* S = (float*)wbase;                      // [21][64] overlay

        v4f acc[16];
        #pragma unroll
        for (int q = 0; q < 16; ++q) acc[q] = (v4f){0.f, 0.f, 0.f, 0.f};

        float4 fa, fb, ca, cb; float m0, m1;
        {
            const size_t jg = (size_t)ibase * NN + j0s + jl;
            fa = *(const float4*)(expansion + jg * 20 + 4 * g);
            fb = *(const float4*)(expansion + (jg + 1) * 20 + 4 * g);
            ca = *(const float4*)(expansion + jg * 20 + 16);
            cb = *(const float4*)(expansion + (jg + 1) * 20 + 16);
            m0 = mask[jg]; m1 = mask[jg + 1];
        }

        for (int it = 0; it < 2; ++it) {
            const int i = ibase + it;
            for (int ch = 0; ch < 2; ++ch) {
                // pack current chunk
                {
                    const float ea[4] = {fa.x, fa.y, fa.z, fa.w};
                    const float eb[4] = {fb.x, fb.y, fb.z, fb.w};
                    #pragma unroll
                    for (int k = 0; k < 4; ++k)
                        *(unsigned*)(L1 + (4 * g + k) * LP + jl) =
                            pack2bf(m0 * ea[k], m1 * eb[k]);
                    if (g == 3) {
                        const float caa[4] = {ca.x, ca.y, ca.z, ca.w};
                        const float cbb[4] = {cb.x, cb.y, cb.z, cb.w};
                        #pragma unroll
                        for (int k = 0; k < 4; ++k)
                            *(unsigned*)(L1 + (16 + k) * LP + jl) =
                                pack2bf(m0 * caa[k], m1 * cbb[k]);
                    }
                    if (g == 0) *(unsigned*)(L1 + 20 * LP + jl) = pack2bf(m0, m1);
                }
                // prefetch next chunk
                {
                    const int u = it * 2 + ch;
                    const int un = (u < 3) ? u + 1 : 3;
                    const size_t jg =
                        (size_t)(ibase + (un >> 1)) * NN + j0s + (un & 1) * 32 + jl;
                    fa = *(const float4*)(expansion + jg * 20 + 4 * g);
                    fb = *(const float4*)(expansion + (jg + 1) * 20 + 4 * g);
                    ca = *(const float4*)(expansion + jg * 20 + 16);
                    cb = *(const float4*)(expansion + (jg + 1) * 20 + 16);
                    m0 = mask[jg]; m1 = mask[jg + 1];
                }
                // MFMA (LDS only)
                {
                    const int ko = quad * 8;
                    const int kl = ch * 32 + ko;
                    const v8s a0 = *(const v8s*)(L1 + lrow * LP + ko);
                    const v8s a1 = *(const v8s*)(L1 + (16 + lrow) * LP + ko);
                    #pragma unroll
                    for (int nt = 0; nt < 8; ++nt) {
                        const v8s b = *(const v8s*)(BSm + (nt * 16 + lrow) * PB + kl);
                        acc[nt]     = MFMA(a0, b, acc[nt]);
                        acc[8 + nt] = MFMA(a1, b, acc[8 + nt]);
                    }
                }
            }
            // epilogue: cols 0..127 of part row
            float* pdst = part + ((size_t)i * NSL + slice) * 224;
            #pragma unroll
            for (int h = 0; h < 2; ++h) {
                #pragma unroll
                for (int mt = 0; mt < 2; ++mt)
                #pragma unroll
                for (int q = 0; q < 4; ++q)
                #pragma unroll
                for (int r = 0; r < 4; ++r) {
                    const int row = mt * 16 + quad * 4 + r;
                    if (row <= 20) S[row * 64 + q * 16 + lrow] = acc[mt * 8 + h * 4 + q][r];
                }
                const int col = h * 64 + lane;
                const int fw = (col < 32) ? (32 + col) : ((col - 32) & 31);
                float v = mR_b[fw] * S[20 * 64 + lane];
                #pragma unroll
                for (int e = 0; e < 20; ++e)
                    v = fmaf(mR_w[e * 96 + fw], S[e * 64 + lane], v);
                pdst[col] = v;
            }
            #pragma unroll
            for (int q = 0; q < 16; ++q) acc[q] = (v4f){0.f, 0.f, 0.f, 0.f};
        }
    } else {
        // ========== T2 wave: rows {m*dir_d*exp_e (60), m*dir_d (3)} x B[128..159]
        unsigned short* L2 = (unsigned short*)wbase;   // [63][LP]
        float* S = (float*)wbase;                      // [63][16] overlay

        v4f acc[8];
        #pragma unroll
        for (int q = 0; q < 8; ++q) acc[q] = (v4f){0.f, 0.f, 0.f, 0.f};

        float4 fa, fb, ca, cb;
        float m0, m1, da0, da1, da2, db0, db1, db2;
        {
            const size_t jg = (size_t)ibase * NN + j0s + jl;
            fa = *(const float4*)(expansion + jg * 20 + 4 * g);
            fb = *(const float4*)(expansion + (jg + 1) * 20 + 4 * g);
            ca = *(const float4*)(expansion + jg * 20 + 16);
            cb = *(const float4*)(expansion + (jg + 1) * 20 + 16);
            m0 = mask[jg]; m1 = mask[jg + 1];
            da0 = direction[jg * 3 + 0]; da1 = direction[jg * 3 + 1]; da2 = direction[jg * 3 + 2];
            db0 = direction[(jg + 1) * 3 + 0]; db1 = direction[(jg + 1) * 3 + 1]; db2 = direction[(jg + 1) * 3 + 2];
        }

        for (int it = 0; it < 2; ++it) {
            const int i = ibase + it;
            for (int ch = 0; ch < 2; ++ch) {
                // pack current chunk
                {
                    const float pa[3] = {m0 * da0, m0 * da1, m0 * da2};
                    const float pb[3] = {m1 * db0, m1 * db1, m1 * db2};
                    const float ea[4] = {fa.x, fa.y, fa.z, fa.w};
                    const float eb[4] = {fb.x, fb.y, fb.z, fb.w};
                    #pragma unroll
                    for (int d = 0; d < 3; ++d)
                        #pragma unroll
                        for (int k = 0; k < 4; ++k)
                            *(unsigned*)(L2 + (d * 20 + 4 * g + k) * LP + jl) =
                                pack2bf(pa[d] * ea[k], pb[d] * eb[k]);
                    if (g < 3) {
                        const float sa = (g == 0) ? pa[0] : ((g == 1) ? pa[1] : pa[2]);
                        const float sb = (g == 0) ? pb[0] : ((g == 1) ? pb[1] : pb[2]);
                        const float caa[4] = {ca.x, ca.y, ca.z, ca.w};
                        const float cbb[4] = {cb.x, cb.y, cb.z, cb.w};
                        #pragma unroll
                        for (int k = 0; k < 4; ++k)
                            *(unsigned*)(L2 + (g * 20 + 16 + k) * LP + jl) =
                                pack2bf(sa * caa[k], sb * cbb[k]);
                    } else {
                        *(unsigned*)(L2 + (60 + 0) * LP + jl) = pack2bf(pa[0], pb[0]);
                        *(unsigned*)(L2 + (60 + 1) * LP + jl) = pack2bf(pa[1], pb[1]);
                        *(unsigned*)(L2 + (60 + 2) * LP + jl) = pack2bf(pa[2], pb[2]);
                    }
                }
                // prefetch next chunk
                {
                    const int u = it * 2 + ch;
                    const int un = (u < 3) ? u + 1 : 3;
                    const size_t jg =
                        (size_t)(ibase + (un >> 1)) * NN + j0s + (un & 1) * 32 + jl;
                    fa = *(const float4*)(expansion + jg * 20 + 4 * g);
                    fb = *(const float4*)(expansion + (jg + 1) * 20 + 4 * g);
                    ca = *(const float4*)(expansion + jg * 20 + 16);
                    cb = *(const float4*)(expansion + (jg + 1) * 20 + 16);
                    m0 = mask[jg]; m1 = mask[jg + 1];
                    da0 = direction[jg * 3 + 0]; da1 = direction[jg * 3 + 1]; da2 = direction[jg * 3 + 2];
                    db0 = direction[(jg + 1) * 3 + 0]; db1 = direction[(jg + 1) * 3 + 1]; db2 = direction[(jg + 1) * 3 + 2];
                }
                // MFMA (LDS only)
                {
                    const int ko = quad * 8;
                    const int kl = ch * 32 + ko;
                    const v8s c0 = *(const v8s*)(L2 + (lrow) * LP + ko);
                    const v8s c1 = *(const v8s*)(L2 + (16 + lrow) * LP + ko);
                    const v8s c2 = *(const v8s*)(L2 + (32 + lrow) * LP + ko);
                    const v8s c3 = *(const v8s*)(L2 + (48 + lrow) * LP + ko);
                    const v8s b0 = *(const v8s*)(BSm + (128 + lrow) * PB + kl);
                    const v8s b1 = *(const v8s*)(BSm + (144 + lrow) * PB + kl);
                    acc[0] = MFMA(c0, b0, acc[0]); acc[1] = MFMA(c0, b1, acc[1]);
                    acc[2] = MFMA(c1, b0, acc[2]); acc[3] = MFMA(c1, b1, acc[3]);
                    acc[4] = MFMA(c2, b0, acc[4]); acc[5] = MFMA(c2, b1, acc[5]);
                    acc[6] = MFMA(c3, b0, acc[6]); acc[7] = MFMA(c3, b1, acc[7]);
                }
            }
            // epilogue: cols 128..223 of part row
            float* pdst = part + ((size_t)i * NSL + slice) * 224;
            #pragma unroll
            for (int h2 = 0; h2 < 2; ++h2) {
                #pragma unroll
                for (int mt = 0; mt < 4; ++mt)
                #pragma unroll
                for (int r = 0; r < 4; ++r) {
                    const int row = mt * 16 + quad * 4 + r;
                    if (row <= 62) S[row * 16 + lrow] = acc[mt * 2 + h2][r];
                }
                if (lane < 48) {
                    const int dd = lane >> 4, f16 = lane & 15;
                    const int f = h2 * 16 + f16;
                    float v = mR_b[64 + f] * S[(60 + dd) * 16 + f16];
                    #pragma unroll
                    for (int e = 0; e < 20; ++e)
                        v = fmaf(mR_w[e * 96 + 64 + f], S[(dd * 20 + e) * 16 + f16], v);
                    pdst[128 + dd * 32 + f] = v;
                }
            }
            #pragma unroll
            for (int q = 0; q < 8; ++q) acc[q] = (v4f){0.f, 0.f, 0.f, 0.f};
        }
    }
}

// ---------------------------------------------------------------------------
// Kernel 3: sum 16 slice-partials + update phase, one block per row.
// ---------------------------------------------------------------------------
extern "C" __global__ __launch_bounds__(256)
void combine_kernel(const float* __restrict__ scalar,
                    const float* __restrict__ vector,
                    const float* __restrict__ uR_w1, const float* __restrict__ uR_b1,
                    const float* __restrict__ uR_w2, const float* __restrict__ uR_b2,
                    const float* __restrict__ U_w,  const float* __restrict__ V_w,
                    const float* __restrict__ part,
                    float* __restrict__ out)
{
    const int i = blockIdx.x;
    const int t = threadIdx.x;
    __shared__ float pcomb[224];
    __shared__ float snew[32], vnew[96];
    __shared__ float lU[96], rV[96], rnorm[32], h2[32], f2[96];

    if (t < 224) {
        const float* p = part + (size_t)i * NSL * 224 + t;
        float a = 0.f;
        #pragma unroll
        for (int s = 0; s < NSL; ++s) a += p[s * 224];
        pcomb[t] = a;
    }
    __syncthreads();

    if (t < 128) {
        const int d = t >> 5, ff = t & 31;
        if (d == 0) snew[ff] = scalar[i * 32 + ff] + pcomb[ff];
        else {
            const int q = t - 32;
            vnew[q] = vector[i * 96 + q] + pcomb[32 + q] + pcomb[128 + q];
        }
    }
    __syncthreads();

    if (t < 96) {
        const int d = t >> 5, ff = t & 31;
        float a = 0.0f;
        #pragma unroll
        for (int k = 0; k < 32; k++) a = fmaf(vnew[d * 32 + k], U_w[k * 32 + ff], a);
        lU[t] = a;
    } else if (t >= 128 && t < 224) {
        const int dt = t - 128, d = dt >> 5, ff = dt & 31;
        float a = 0.0f;
        #pragma unroll
        for (int k = 0; k < 32; k++) a = fmaf(vnew[d * 32 + k], V_w[k * 32 + ff], a);
        rV[dt] = a;
    }
    __syncthreads();
    if (t < 32) {
        const float a = rV[t] * rV[t] + rV[32 + t] * rV[32 + t] + rV[64 + t] * rV[64 + t];
        rnorm[t] = sqrtf(a);
    }
    __syncthreads();
    if (t < 32) {
        float a = uR_b1[t];
        #pragma unroll
        for (int k = 0; k < 32; k++) a = fmaf(snew[k],  uR_w1[k * 32 + t], a);
        #pragma unroll
        for (int k = 0; k < 32; k++) a = fmaf(rnorm[k], uR_w1[(32 + k) * 32 + t], a);
        h2[t] = silu_f(a);
    }
    __syncthreads();
    if (t < 96) {
        float a = uR_b2[t];
        #pragma unroll
        for (int k = 0; k < 32; k++) a = fmaf(h2[k], uR_w2[k * 96 + t], a);
        f2[t] = a;
    }
    __syncthreads();
    if (t < 32) {
        const float inner = lU[t] * rV[t] + lU[32 + t] * rV[32 + t] + lU[64 + t] * rV[64 + t];
        out[i * 32 + t] = snew[t] + inner * f2[32 + t] + f2[64 + t];
    } else if (t >= 64 && t < 160) {
        const int dt = t - 64, ff = dt & 31;
        out[32768 + i * 96 + dt] = vnew[dt] + f2[ff] * lU[dt];
    }
}

extern "C" void kernel_launch(void* const* d_in, const int* in_sizes, int n_in,
                              void* d_out, int out_size, void* d_ws, size_t ws_size,
                              hipStream_t stream) {
    const float* scalar    = (const float*)d_in[0];
    const float* vector    = (const float*)d_in[1];
    const float* expansion = (const float*)d_in[2];
    const float* direction = (const float*)d_in[3];
    const float* mask      = (const float*)d_in[4];
    const float* mL_w1     = (const float*)d_in[5];
    const float* mL_b1     = (const float*)d_in[6];
    const float* mL_w2     = (const float*)d_in[7];
    const float* mL_b2     = (const float*)d_in[8];
    const float* mR_w      = (const float*)d_in[9];
    const float* mR_b      = (const float*)d_in[10];
    const float* uR_w1     = (const float*)d_in[11];
    const float* uR_b1     = (const float*)d_in[12];
    const float* uR_w2     = (const float*)d_in[13];
    const float* uR_b2     = (const float*)d_in[14];
    const float* U_w       = (const float*)d_in[15];
    const float* V_w       = (const float*)d_in[16];
    float* out = (float*)d_out;

    unsigned short* RT = (unsigned short*)d_ws;                 // 320 KB
    float* part = (float*)((char*)d_ws + 160 * NN * 2);         // 1024*16*224*4 = 14.7 MB

    hipLaunchKernelGGL(node_kernel, dim3(NN), dim3(128), 0, stream,
                       scalar, vector, mL_w1, mL_b1, mL_w2, mL_b2, RT);
    hipLaunchKernelGGL(edge_mfma_kernel, dim3(4096), dim3(256), 0, stream,
                       expansion, direction, mask, mR_w, mR_b, RT, part);
    hipLaunchKernelGGL(combine_kernel, dim3(NN), dim3(256), 0, stream,
                       scalar, vector, uR_w1, uR_b1, uR_w2, uR_b2, U_w, V_w,
                       part, out);
}